// Round 1
// baseline (30.662 us; speedup 1.0000x reference)
//
#include <hip/hip_runtime.h>

// NeRF ray composition: rgb / accumulated_weights / depth / disparity.
// One block (256 threads) per ray; 1024 points per ray -> 4 points/thread.
// Exclusive cumprod of (1 - alpha + 1e-10) via wave shfl scan + LDS wave
// offsets; block shuffle reduction for the 5 accumulated quantities.

#define NUM_RAYS 8192
#define P 1024
#define BLOCK 256

__global__ __launch_bounds__(256) void compose_rays_kernel(
    const float* __restrict__ rgb_in,     // [R, P, 3]
    const float* __restrict__ raw_alpha,  // [R, P]
    const float* __restrict__ z_vals,     // [R, P]
    const float* __restrict__ rays_dir,   // [R, 3]
    const int*   __restrict__ ppr,        // [1]
    float* __restrict__ out)              // rgb[3R] | acc[R] | depth[R] | disp[R]
{
    const int r    = blockIdx.x;
    const int t    = threadIdx.x;
    const int lane = t & 63;
    const int wid  = t >> 6;

    const float cf = (float)(*ppr) * (1.0f / 1024.0f);

    // per-ray direction norm (tiny, broadcast-cached loads)
    const float dx = rays_dir[r * 3 + 0];
    const float dy = rays_dir[r * 3 + 1];
    const float dz = rays_dir[r * 3 + 2];
    const float nrm = sqrtf(dx * dx + dy * dy + dz * dz);

    const size_t rowP = (size_t)r * P;
    const float4 a4 = *(const float4*)(raw_alpha + rowP + 4 * t);
    const float4 z4 = *(const float4*)(z_vals    + rowP + 4 * t);
    float z_next = 0.0f;
    if (t < BLOCK - 1) z_next = z_vals[rowP + 4 * t + 4];

    float av[4] = {a4.x, a4.y, a4.z, a4.w};
    float zv[4] = {z4.x, z4.y, z4.z, z4.w};
    float dists[4];
    dists[0] = (z4.y - z4.x) * nrm;
    dists[1] = (z4.z - z4.y) * nrm;
    dists[2] = (z4.w - z4.z) * nrm;
    dists[3] = ((t == BLOCK - 1) ? 1e10f : (z_next - z4.w)) * nrm;

    float alpha[4], om[4];
    float local_prod = 1.0f;
#pragma unroll
    for (int j = 0; j < 4; ++j) {
        float ra = fmaxf(av[j], 0.0f);
        alpha[j] = 1.0f - expf(-ra * dists[j] * cf);
        om[j]    = 1.0f - alpha[j] + 1e-10f;
        local_prod *= om[j];
    }

    // --- multiplicative inclusive scan of per-thread products within wave ---
    float v = local_prod;
#pragma unroll
    for (int off = 1; off < 64; off <<= 1) {
        float n = __shfl_up(v, off);
        if (lane >= off) v *= n;
    }

    __shared__ float wave_tot[4];
    __shared__ float red[4][5];
    __shared__ float last_wz[2];  // weight[P-1], z[P-1]
    if (lane == 63) wave_tot[wid] = v;
    __syncthreads();

    // exclusive prefix for this thread
    float excl = __shfl_up(v, 1);
    if (lane == 0) excl = 1.0f;
#pragma unroll
    for (int w = 0; w < 3; ++w)
        if (wid > w) excl *= wave_tot[w];

    // --- rgb loads (12 consecutive floats per thread) ---
    const float* rgbp = rgb_in + (size_t)r * (P * 3) + 12 * t;
    const float4 c0 = *(const float4*)(rgbp + 0);
    const float4 c1 = *(const float4*)(rgbp + 4);
    const float4 c2 = *(const float4*)(rgbp + 8);
    float rgbv[12] = {c0.x, c0.y, c0.z, c0.w, c1.x, c1.y, c1.z, c1.w,
                      c2.x, c2.y, c2.z, c2.w};

    float trun = excl;
    float ws = 0.f, rs = 0.f, gs = 0.f, bs = 0.f, ds = 0.f;
#pragma unroll
    for (int j = 0; j < 4; ++j) {
        float w = alpha[j] * trun;
        ws += w;
        rs += w * rgbv[3 * j + 0];
        gs += w * rgbv[3 * j + 1];
        bs += w * rgbv[3 * j + 2];
        if (4 * t + j < P - 1) {
            ds += w * zv[j];
        } else {
            last_wz[0] = w;      // only thread 255, j==3 hits this
            last_wz[1] = zv[j];
        }
        trun *= om[j];
    }

    // --- block reduction of 5 values ---
#pragma unroll
    for (int off = 32; off > 0; off >>= 1) {
        ws += __shfl_down(ws, off);
        rs += __shfl_down(rs, off);
        gs += __shfl_down(gs, off);
        bs += __shfl_down(bs, off);
        ds += __shfl_down(ds, off);
    }
    if (lane == 0) {
        red[wid][0] = ws; red[wid][1] = rs; red[wid][2] = gs;
        red[wid][3] = bs; red[wid][4] = ds;
    }
    __syncthreads();

    if (t == 0) {
        float W = 0.f, R_ = 0.f, G = 0.f, B = 0.f, D = 0.f;
#pragma unroll
        for (int w = 0; w < 4; ++w) {
            W  += red[w][0];
            R_ += red[w][1];
            G  += red[w][2];
            B  += red[w][3];
            D  += red[w][4];
        }
        const float wl = last_wz[0];
        const float zl = last_wz[1];
        const float depth = D + (1.0f - W + wl) * zl;
        const float disp  = 1.0f / fmaxf(1e-4f, depth / W);
        out[r * 3 + 0] = R_;
        out[r * 3 + 1] = G;
        out[r * 3 + 2] = B;
        out[3 * NUM_RAYS + r] = W;
        out[4 * NUM_RAYS + r] = depth;
        out[5 * NUM_RAYS + r] = disp;
    }
}

extern "C" void kernel_launch(void* const* d_in, const int* in_sizes, int n_in,
                              void* d_out, int out_size, void* d_ws, size_t ws_size,
                              hipStream_t stream) {
    const float* rgb_in    = (const float*)d_in[0];  // [8192,1024,3]
    const float* raw_alpha = (const float*)d_in[1];  // [8192,1024]
    const float* z_vals    = (const float*)d_in[2];  // [8192,1024]
    const float* rays_dir  = (const float*)d_in[3];  // [8192,3]
    // d_in[4] = pruning_mask (unused by the reference math)
    const int*   ppr       = (const int*)d_in[5];    // [1]
    float* out = (float*)d_out;

    compose_rays_kernel<<<NUM_RAYS, BLOCK, 0, stream>>>(
        rgb_in, raw_alpha, z_vals, rays_dir, ppr, out);
}